// Round 1
// baseline (8482.754 us; speedup 1.0000x reference)
//
#include <hip/hip_runtime.h>

// AdEx Euler integration, bit-faithful fp32 port of the jax/numpy reference.
// Sequential scan over T=40000 steps; N=1024 independent neurons -> 16 waves.
// Latency-bound on the per-step dependent chain; correctness requires exact
// fp32 op order (spike timing amplifies ulp-level differences ~1000x).

__global__ void __launch_bounds__(64, 1) adex_kernel(
    const float* __restrict__ I_ext,
    const float* __restrict__ V0,
    const float* __restrict__ w0,
    const float* __restrict__ p_V_rest,
    const float* __restrict__ p_V_reset,
    const float* __restrict__ p_V_T,
    const float* __restrict__ p_V_thres,
    const float* __restrict__ p_delta_T,
    const float* __restrict__ p_R,
    const float* __restrict__ p_tau,
    const float* __restrict__ p_tau_w,
    const float* __restrict__ p_a,
    const float* __restrict__ p_b,
    float* __restrict__ out,
    int T, int N)
{
    // No FMA contraction: reference (numpy/XLA fp32) uses separate mul+add
    // rounding; contraction would change rounding and risk spike-time flips.
#pragma clang fp contract(off)
    const int n = blockIdx.x * blockDim.x + threadIdx.x;
    if (n >= N) return;

    const float dt      = 5e-5f;           // DT hardcoded in reference
    const float V_rest  = *p_V_rest;
    const float V_reset = *p_V_reset;
    const float V_T     = *p_V_T;
    const float V_thres = *p_V_thres;
    const float delta_T = *p_delta_T;
    const float R       = *p_R;
    const float tau     = *p_tau;
    const float tau_w   = *p_tau_w;
    const float a       = *p_a;
    const float b       = *p_b;
    // b/dt is a single fp32 division in the reference too (scalar broadcast);
    // hoisting it is bit-identical.
    const float b_over_dt = b / dt;

    float V = V0[n];
    float w = w0[n];

    float* outV = out + n;
    float* outW = out + (size_t)T * N + n;

    // I_ext is uniform across the wave (scalar loads). Pipeline 2 deep so the
    // load latency stays off the ~100-cycle dependent chain. I_ext has T+5
    // elements, so k+2 <= T+1 is always in bounds.
    float I0 = I_ext[0];
    float I1 = I_ext[1];

    for (int k = 0; k < T; ++k) {
        float I2 = I_ext[k + 2];

        // Emit pre-step state: solution[k] = state after k steps.
        outV[(size_t)k * N] = V;
        outW[(size_t)k * N] = w;

        // dvdt = (-(V - V_rest) + delta_T*exp((V - V_T)/delta_T) - R*w + R*I)/tau
        // evaluated left-to-right exactly as Python parses it.
        float t1   = V - V_rest;
        float ex   = expf((V - V_T) / delta_T);
        float s    = (-t1) + (delta_T * ex);
        s          = s - (R * w);
        s          = s + (R * I0);
        float dvdt = s / tau;

        // dwdt = (a*(V - V_rest) - w) / tau_w
        float tw   = (a * t1) - w;
        float dwdt = tw / tau_w;

        // spike branch (uses pre-update V): hard reset expressed through the
        // same divide-then-multiply round trip as the reference.
        bool  spike  = V > V_thres;
        float dvdt_s = (V_reset - V) / dt;
        dvdt = spike ? dvdt_s : dvdt;
        dwdt = spike ? (dwdt + b_over_dt) : dwdt;

        V = V + (dt * dvdt);
        w = w + (dt * dwdt);

        I0 = I1;
        I1 = I2;
    }
}

extern "C" void kernel_launch(void* const* d_in, const int* in_sizes, int n_in,
                              void* d_out, int out_size, void* d_ws, size_t ws_size,
                              hipStream_t stream) {
    const float* I_ext = (const float*)d_in[0];
    const float* V0    = (const float*)d_in[1];
    const float* w0    = (const float*)d_in[2];

    const int N = in_sizes[1];          // 1024
    const int T = out_size / (2 * N);   // 40000

    const int block = 64;
    const int grid  = (N + block - 1) / block;   // 16 blocks -> 16 CUs

    adex_kernel<<<grid, block, 0, stream>>>(
        I_ext, V0, w0,
        (const float*)d_in[3],  // V_rest
        (const float*)d_in[4],  // V_reset
        (const float*)d_in[5],  // V_T
        (const float*)d_in[6],  // V_thres
        (const float*)d_in[7],  // delta_T
        (const float*)d_in[8],  // R
        (const float*)d_in[9],  // tau
        (const float*)d_in[10], // tau_w
        (const float*)d_in[11], // a
        (const float*)d_in[12], // b
        (float*)d_out, T, N);
}

// Round 2
// 7310.999 us; speedup vs baseline: 1.1603x; 1.1603x over previous
//
#include <hip/hip_runtime.h>

// AdEx Euler integration, bit-faithful fp32 port of the jax/numpy reference.
// Sequential scan over T=40000 steps; N=1024 independent neurons -> 16 waves.
// Latency-bound on the per-step dependent chain; correctness requires exact
// fp32 op order (spike timing amplifies ulp-level differences ~1000x).
//
// R1 change: I_ext is wave-uniform -> scalar loads. Batch them 8 at a time
// (s_load_dwordx8-mergeable), double-buffered A/B with prefetch distance of
// 8 steps (~1000+ cyc) so scalar-load latency is fully off the carried chain.
// Numerics are bit-identical to R0 (absmax must stay 4.882812e-04).

__global__ void __launch_bounds__(64, 1) adex_kernel(
    const float* __restrict__ I_ext,
    const float* __restrict__ V0,
    const float* __restrict__ w0,
    const float* __restrict__ p_V_rest,
    const float* __restrict__ p_V_reset,
    const float* __restrict__ p_V_T,
    const float* __restrict__ p_V_thres,
    const float* __restrict__ p_delta_T,
    const float* __restrict__ p_R,
    const float* __restrict__ p_tau,
    const float* __restrict__ p_tau_w,
    const float* __restrict__ p_a,
    const float* __restrict__ p_b,
    float* __restrict__ out,
    int T, int N)
{
    // No FMA contraction: reference fp32 uses separate mul+add rounding.
#pragma clang fp contract(off)
    int n = blockIdx.x * blockDim.x + threadIdx.x;
    if (n >= N) n = N - 1;   // no early-return: keep control flow uniform so
                             // uniform loads stay scalar (s_load). Duplicate
                             // threads (never happens at N%64==0) would write
                             // identical values - benign.

    const float dt      = 5e-5f;
    const float V_rest  = *p_V_rest;
    const float V_reset = *p_V_reset;
    const float V_T     = *p_V_T;
    const float V_thres = *p_V_thres;
    const float delta_T = *p_delta_T;
    const float R       = *p_R;
    const float tau     = *p_tau;
    const float tau_w   = *p_tau_w;
    const float a       = *p_a;
    const float b       = *p_b;
    const float b_over_dt = b / dt;   // single fp32 div, bit-identical hoist

    float V = V0[n];
    float w = w0[n];

    float* outV = out + n;
    float* outW = out + (size_t)T * N + n;

    // One Euler step, exact op order of the reference.
#define ADEX_STEP(I_k)                                              \
    {                                                               \
        outV[0] = V;                                                \
        outW[0] = w;                                                \
        outV += N;                                                  \
        outW += N;                                                  \
        float t1   = V - V_rest;                                    \
        float ex   = expf((V - V_T) / delta_T);                     \
        float s    = (-t1) + (delta_T * ex);                        \
        s          = s - (R * w);                                   \
        s          = s + (R * (I_k));                               \
        float dvdt = s / tau;                                       \
        float tw   = (a * t1) - w;                                  \
        float dwdt = tw / tau_w;                                    \
        bool  spike  = V > V_thres;                                 \
        float dvdt_s = (V_reset - V) / dt;                          \
        dvdt = spike ? dvdt_s : dvdt;                               \
        dwdt = spike ? (dwdt + b_over_dt) : dwdt;                   \
        V = V + (dt * dvdt);                                        \
        w = w + (dt * dwdt);                                        \
    }

    // Double-buffered uniform I batches. I_ext has T+5 elements; clamp the
    // prefetch base so reads never pass T+4 (clamped batches are only
    // partially consumed, values still correct for k < T).
    float A[8], B[8];
#pragma unroll
    for (int j = 0; j < 8; ++j) A[j] = I_ext[j];

    for (int kb = 0; kb < T; kb += 16) {
        // prefetch batch B = I[kb+8 .. kb+15] (kb <= T-16 -> max idx T-1, ok)
#pragma unroll
        for (int j = 0; j < 8; ++j) B[j] = I_ext[kb + 8 + j];

#pragma unroll
        for (int j = 0; j < 8; ++j) ADEX_STEP(A[j]);

        // prefetch batch A = I[kb+16 .. kb+23], clamped to stay in bounds
        {
            int pb = kb + 16;
            if (pb > T - 3) pb = T - 3;   // pb+7 <= T+4
#pragma unroll
            for (int j = 0; j < 8; ++j) A[j] = I_ext[pb + j];
        }

#pragma unroll
        for (int j = 0; j < 8; ++j) ADEX_STEP(B[j]);
    }
#undef ADEX_STEP
}

extern "C" void kernel_launch(void* const* d_in, const int* in_sizes, int n_in,
                              void* d_out, int out_size, void* d_ws, size_t ws_size,
                              hipStream_t stream) {
    const float* I_ext = (const float*)d_in[0];
    const float* V0    = (const float*)d_in[1];
    const float* w0    = (const float*)d_in[2];

    const int N = in_sizes[1];          // 1024
    const int T = out_size / (2 * N);   // 40000

    const int block = 64;
    const int grid  = (N + block - 1) / block;   // 16 blocks

    adex_kernel<<<grid, block, 0, stream>>>(
        I_ext, V0, w0,
        (const float*)d_in[3],  // V_rest
        (const float*)d_in[4],  // V_reset
        (const float*)d_in[5],  // V_T
        (const float*)d_in[6],  // V_thres
        (const float*)d_in[7],  // delta_T
        (const float*)d_in[8],  // R
        (const float*)d_in[9],  // tau
        (const float*)d_in[10], // tau_w
        (const float*)d_in[11], // a
        (const float*)d_in[12], // b
        (float*)d_out, T, N);
}

// Round 3
// 4466.038 us; speedup vs baseline: 1.8994x; 1.6370x over previous
//
#include <hip/hip_runtime.h>

// AdEx Euler integration, bit-faithful fp32 port of the jax/numpy reference.
// Sequential scan over T=40000 steps; N=1024 neurons -> 16 waves. Wall time
// floor = T x per-step dependent-chain latency; only chain shortening helps.
//
// R1: batched uniform I_ext scalar loads, double-buffered (8217 -> 7055 us).
// R2: replace all four IEEE fp32 divides per step with fp64 reciprocal-
//     multiply: (float)((double)x * (1.0/(double)y)), reciprocal hoisted.
//     By Markstein (needs >= 2p+2 = 50 bits; fp64 has 53), this rounds
//     identically to IEEE fp32 division for all normal inputs -> bit-exact
//     (absmax must stay exactly 4.882812e-04). Each div: ~10 instrs/~45 cyc
//     -> 3 instrs/~16 cyc, two of them on the V dependent chain.

__device__ __forceinline__ float fdiv_via_f64(float x, double inv_y) {
    return (float)((double)x * inv_y);
}

__global__ void __launch_bounds__(64, 1) adex_kernel(
    const float* __restrict__ I_ext,
    const float* __restrict__ V0,
    const float* __restrict__ w0,
    const float* __restrict__ p_V_rest,
    const float* __restrict__ p_V_reset,
    const float* __restrict__ p_V_T,
    const float* __restrict__ p_V_thres,
    const float* __restrict__ p_delta_T,
    const float* __restrict__ p_R,
    const float* __restrict__ p_tau,
    const float* __restrict__ p_tau_w,
    const float* __restrict__ p_a,
    const float* __restrict__ p_b,
    float* __restrict__ out,
    int T, int N)
{
    // No implicit FMA contraction: reference fp32 uses separate mul+add
    // rounding. (Explicit fmaf would still be honored, but we use none.)
#pragma clang fp contract(off)
    int n = blockIdx.x * blockDim.x + threadIdx.x;
    if (n >= N) n = N - 1;   // keep control flow uniform (scalar I loads)

    const float dt      = 5e-5f;
    const float V_rest  = *p_V_rest;
    const float V_reset = *p_V_reset;
    const float V_T     = *p_V_T;
    const float V_thres = *p_V_thres;
    const float delta_T = *p_delta_T;
    const float R       = *p_R;
    const float tau     = *p_tau;
    const float tau_w   = *p_tau_w;
    const float a       = *p_a;
    const float b       = *p_b;
    const float b_over_dt = b / dt;   // once, off-loop (bit-identical hoist)

    // Hoisted f64 reciprocals (one IEEE f64 div each, off-loop).
    const double inv_delta_T = 1.0 / (double)delta_T;
    const double inv_tau     = 1.0 / (double)tau;
    const double inv_tau_w   = 1.0 / (double)tau_w;
    const double inv_dt      = 1.0 / (double)dt;

    float V = V0[n];
    float w = w0[n];

    float* outV = out + n;
    float* outW = out + (size_t)T * N + n;

    // One Euler step, exact op order of the reference. RI_k = R*I_k is
    // precomputed per batch (identical single rounding).
#define ADEX_STEP(RI_k)                                             \
    {                                                               \
        outV[0] = V;                                                \
        outW[0] = w;                                                \
        outV += N;                                                  \
        outW += N;                                                  \
        float t1   = V - V_rest;                                    \
        float ex   = expf(fdiv_via_f64(V - V_T, inv_delta_T));      \
        float s    = (-t1) + (delta_T * ex);                        \
        s          = s - (R * w);                                   \
        s          = s + (RI_k);                                    \
        float dvdt = fdiv_via_f64(s, inv_tau);                      \
        float tw   = (a * t1) - w;                                  \
        float dwdt = fdiv_via_f64(tw, inv_tau_w);                   \
        bool  spike  = V > V_thres;                                 \
        float dvdt_s = fdiv_via_f64(V_reset - V, inv_dt);           \
        dvdt = spike ? dvdt_s : dvdt;                               \
        dwdt = spike ? (dwdt + b_over_dt) : dwdt;                   \
        V = V + (dt * dvdt);                                        \
        w = w + (dt * dwdt);                                        \
    }

    // Double-buffered uniform I batches (R*I precomputed, off-chain).
    float A[8], B[8];
#pragma unroll
    for (int j = 0; j < 8; ++j) A[j] = R * I_ext[j];

    for (int kb = 0; kb < T; kb += 16) {
#pragma unroll
        for (int j = 0; j < 8; ++j) B[j] = R * I_ext[kb + 8 + j];

#pragma unroll
        for (int j = 0; j < 8; ++j) ADEX_STEP(A[j]);

        {
            int pb = kb + 16;
            if (pb > T - 3) pb = T - 3;   // clamp: pb+7 <= T+4 (I has T+5)
#pragma unroll
            for (int j = 0; j < 8; ++j) A[j] = R * I_ext[pb + j];
        }

#pragma unroll
        for (int j = 0; j < 8; ++j) ADEX_STEP(B[j]);
    }
#undef ADEX_STEP
}

extern "C" void kernel_launch(void* const* d_in, const int* in_sizes, int n_in,
                              void* d_out, int out_size, void* d_ws, size_t ws_size,
                              hipStream_t stream) {
    const float* I_ext = (const float*)d_in[0];
    const float* V0    = (const float*)d_in[1];
    const float* w0    = (const float*)d_in[2];

    const int N = in_sizes[1];          // 1024
    const int T = out_size / (2 * N);   // 40000

    const int block = 64;
    const int grid  = (N + block - 1) / block;   // 16 blocks

    adex_kernel<<<grid, block, 0, stream>>>(
        I_ext, V0, w0,
        (const float*)d_in[3],  // V_rest
        (const float*)d_in[4],  // V_reset
        (const float*)d_in[5],  // V_T
        (const float*)d_in[6],  // V_thres
        (const float*)d_in[7],  // delta_T
        (const float*)d_in[8],  // R
        (const float*)d_in[9],  // tau
        (const float*)d_in[10], // tau_w
        (const float*)d_in[11], // a
        (const float*)d_in[12], // b
        (float*)d_out, T, N);
}

// Round 4
// 4272.041 us; speedup vs baseline: 1.9856x; 1.0454x over previous
//
#include <hip/hip_runtime.h>

// AdEx Euler integration, bit-faithful fp32 port of the jax/numpy reference.
// Sequential scan over T=40000 steps; N=1024 neurons -> 16 waves on 16 CUs,
// one wave per CU. Wall time floor = T x per-step dependent-chain latency.
//
// R1: batched uniform I_ext scalar loads, double-buffered   8217 -> 7055 us
// R2: IEEE divs -> fp64 reciprocal-mul (Markstein, bit-exact) 7055 -> 4193 us
// R3: VGPR_Count was 16 -> allocator aliased store-data regs with the
//     loop-carried V/w, forcing s_waitcnt vmcnt WAR stalls (~100 cyc/iter,
//     store completion ~200+ cyc) on a single in-order wave. Buffer 16
//     steps' outputs in explicit register arrays and burst-store per batch:
//     forces >=32 extra live VGPRs, pushes store-reg reuse ~2000 cyc away,
//     lets the scheduler sink stores into chain bubbles.
//     Numerics untouched: absmax must stay exactly 4.882812e-04.

__device__ __forceinline__ float fdiv_via_f64(float x, double inv_y) {
    return (float)((double)x * inv_y);
}

__global__ void __launch_bounds__(64, 1) adex_kernel(
    const float* __restrict__ I_ext,
    const float* __restrict__ V0,
    const float* __restrict__ w0,
    const float* __restrict__ p_V_rest,
    const float* __restrict__ p_V_reset,
    const float* __restrict__ p_V_T,
    const float* __restrict__ p_V_thres,
    const float* __restrict__ p_delta_T,
    const float* __restrict__ p_R,
    const float* __restrict__ p_tau,
    const float* __restrict__ p_tau_w,
    const float* __restrict__ p_a,
    const float* __restrict__ p_b,
    float* __restrict__ out,
    int T, int N)
{
    // No FMA contraction: reference fp32 uses separate mul+add rounding.
#pragma clang fp contract(off)
    int n = blockIdx.x * blockDim.x + threadIdx.x;
    if (n >= N) n = N - 1;   // keep control flow uniform (scalar I loads)

    const float dt      = 5e-5f;
    const float V_rest  = *p_V_rest;
    const float V_reset = *p_V_reset;
    const float V_T     = *p_V_T;
    const float V_thres = *p_V_thres;
    const float delta_T = *p_delta_T;
    const float R       = *p_R;
    const float tau     = *p_tau;
    const float tau_w   = *p_tau_w;
    const float a       = *p_a;
    const float b       = *p_b;
    const float b_over_dt = b / dt;   // once, off-loop (bit-identical hoist)

    // Hoisted f64 reciprocals (one IEEE f64 div each, off-loop). Markstein:
    // f64 mul by correctly-rounded f64 reciprocal rounds identically to
    // IEEE f32 division for all normal inputs.
    const double inv_delta_T = 1.0 / (double)delta_T;
    const double inv_tau     = 1.0 / (double)tau;
    const double inv_tau_w   = 1.0 / (double)tau_w;
    const double inv_dt      = 1.0 / (double)dt;

    float V = V0[n];
    float w = w0[n];

    float* outV = out + n;
    float* outW = out + (size_t)T * N + n;

    // One Euler step, exact op order of the reference; emits pre-step state
    // into register buffers (distinct regs per j -> no store-WAR aliasing).
#define ADEX_STEP(j, RI_k)                                          \
    {                                                               \
        oV[j] = V;                                                  \
        ow[j] = w;                                                  \
        float t1   = V - V_rest;                                    \
        float ex   = expf(fdiv_via_f64(V - V_T, inv_delta_T));      \
        float s    = (-t1) + (delta_T * ex);                        \
        s          = s - (R * w);                                   \
        s          = s + (RI_k);                                    \
        float dvdt = fdiv_via_f64(s, inv_tau);                      \
        float tw   = (a * t1) - w;                                  \
        float dwdt = fdiv_via_f64(tw, inv_tau_w);                   \
        bool  spike  = V > V_thres;                                 \
        float dvdt_s = fdiv_via_f64(V_reset - V, inv_dt);           \
        dvdt = spike ? dvdt_s : dvdt;                               \
        dwdt = spike ? (dwdt + b_over_dt) : dwdt;                   \
        V = V + (dt * dvdt);                                        \
        w = w + (dt * dwdt);                                        \
    }

    // Double-buffered uniform I batches (R*I precomputed, off-chain).
    // I_ext has T+5 elements; prefetch base clamped so max index <= T+4.
    float A[16], B[16];
    float oV[16], ow[16];
#pragma unroll
    for (int j = 0; j < 16; ++j) A[j] = R * I_ext[j];

    for (int kb = 0; kb < T; kb += 32) {
        // prefetch B = I[kb+16 .. kb+31]  (kb <= T-32 -> max idx T-1, ok)
#pragma unroll
        for (int j = 0; j < 16; ++j) B[j] = R * I_ext[kb + 16 + j];

#pragma unroll
        for (int j = 0; j < 16; ++j) ADEX_STEP(j, A[j]);
#pragma unroll
        for (int j = 0; j < 16; ++j) { outV[(size_t)j * N] = oV[j];
                                       outW[(size_t)j * N] = ow[j]; }
        outV += (size_t)16 * N;
        outW += (size_t)16 * N;

        // prefetch A = I[kb+32 .. kb+47], clamped (pb+15 <= T+4)
        {
            int pb = kb + 32;
            if (pb > T - 11) pb = T - 11;
#pragma unroll
            for (int j = 0; j < 16; ++j) A[j] = R * I_ext[pb + j];
        }

#pragma unroll
        for (int j = 0; j < 16; ++j) ADEX_STEP(j, B[j]);
#pragma unroll
        for (int j = 0; j < 16; ++j) { outV[(size_t)j * N] = oV[j];
                                       outW[(size_t)j * N] = ow[j]; }
        outV += (size_t)16 * N;
        outW += (size_t)16 * N;
    }
#undef ADEX_STEP
}

extern "C" void kernel_launch(void* const* d_in, const int* in_sizes, int n_in,
                              void* d_out, int out_size, void* d_ws, size_t ws_size,
                              hipStream_t stream) {
    const float* I_ext = (const float*)d_in[0];
    const float* V0    = (const float*)d_in[1];
    const float* w0    = (const float*)d_in[2];

    const int N = in_sizes[1];          // 1024
    const int T = out_size / (2 * N);   // 40000

    const int block = 64;
    const int grid  = (N + block - 1) / block;   // 16 blocks

    adex_kernel<<<grid, block, 0, stream>>>(
        I_ext, V0, w0,
        (const float*)d_in[3],  // V_rest
        (const float*)d_in[4],  // V_reset
        (const float*)d_in[5],  // V_T
        (const float*)d_in[6],  // V_thres
        (const float*)d_in[7],  // delta_T
        (const float*)d_in[8],  // R
        (const float*)d_in[9],  // tau
        (const float*)d_in[10], // tau_w
        (const float*)d_in[11], // a
        (const float*)d_in[12], // b
        (float*)d_out, T, N);
}